// Round 8
// baseline (2118.487 us; speedup 1.0000x reference)
//
#include <hip/hip_runtime.h>

#define SS 8
#define NN 5000
#define NNSQ 25000000
#define DD 128
#define RB 8          // rows per block
#define JS 4          // column splits (partials)
#define JT 32         // tile columns
#define TPB 40        // tiles per block (4*40*32 = 5120 >= 5000)
#define RG 625        // row groups

typedef float f4 __attribute__((ext_vector_type(4)));

typedef const __attribute__((address_space(1))) void glb_void;
typedef __attribute__((address_space(3))) void lds_void;

__device__ __forceinline__ void gld_lds16(const void* g, void* l) {
    __builtin_amdgcn_global_load_lds((glb_void*)g, (lds_void*)l, 16, 0, 0);
}

#define VMCNT0 asm volatile("s_waitcnt vmcnt(0)" ::: "memory")
#define SB0    __builtin_amdgcn_sched_barrier(0)

// Single-wave workgroups: each wave is a fully independent pipeline over an
// 8-row x 1280-col strip (40 tiles of 32 cols). No barriers anywhere.
// ~10 waves resident per CU stagger naturally and keep the HBM queue fed.
__global__ __launch_bounds__(64, 4)
void diffuse_spmm(const float* __restrict__ theta,
                  const float* __restrict__ Tm,
                  const float* __restrict__ x,
                  const float* __restrict__ am,
                  float* __restrict__ ws)
{
    __shared__ float stg[SS + 1][RB * JT];   // 9.2 KB: [slice][row8*col32]; slice 8 = a
    __shared__ float qv[2][RB * JT];         // 2 KB double-buffered q tile

    const int lane = threadIdx.x;            // 0..63 (one wave)
    const int rg   = blockIdx.x % RG;
    const int js   = blockIdx.x / RG;
    const int i0   = rg * RB;
    const int jblk = js * (TPB * JT);

    // staging mapping: lane l -> (row = l>>3, col = (l&7)*4); DMA writes lane*16B
    const int srow = lane >> 3;
    const int scol = (lane & 7) << 2;
    const int lb   = lane << 2;              // == srow*32 + scol
    // Phase B mapping: 32 d-slots x 2 j-halves
    const int d0   = (lane & 31) << 2;
    const int jh   = lane >> 5;

    float th[SS];
#pragma unroll
    for (int s = 0; s < SS; ++s) th[s] = theta[s];

    // DMA tile m's 8 T-slices + a into stg (0 VGPR cost; every HBM segment 128 B)
    auto stage_dma = [&](int m) {
        const int jg = jblk + m * JT + scol;
        if (jg < NN) {                       // per-lane exec mask (ragged tiles)
            const size_t goff = (size_t)(i0 + srow) * NN + jg;
#pragma unroll
            for (int s = 0; s < SS; ++s)
                gld_lds16(Tm + (size_t)s * NNSQ + goff, &stg[s][0]);
            gld_lds16(am + goff, &stg[SS][0]);
        }
    };

    // q for tile m -> qv[buf] (wave-private; stage fully drained before call)
    auto qcompute = [&](int m, int buf) {
        const int jg = jblk + m * JT + scol;
        f4 ssum = (*(const f4*)&stg[0][lb]) * th[0];
#pragma unroll
        for (int s = 1; s < SS; ++s)
            ssum += (*(const f4*)&stg[s][lb]) * th[s];
        f4 q = (*(const f4*)&stg[SS][lb]) * ssum;
        if (jg >= NN) q = (f4)(0.0f);        // mask stale LDS on ragged tiles
        *(f4*)&qv[buf][lb] = q;
    };

    f4 acc[RB];
#pragma unroll
    for (int r = 0; r < RB; ++r) acc[r] = (f4)(0.0f);

    // ---- prologue: stage tile 0, drain, q(0) ----
    stage_dma(0);
    VMCNT0; SB0;
    qcompute(0, 0);

    // ---- body: xv (FIFO head) -> dma(k+1) (FIFO tail) -> Phase B -> drain -> q(k+1)
    auto body = [&](int k, int buf) {
        f4 xv[16];                           // static indexing only
        {
            const int jb = jblk + k * JT + (jh << 4);
#pragma unroll
            for (int q = 0; q < 16; ++q) {
                const int j = jb + q;
                if (j < NN) xv[q] = *(const f4*)(x + (size_t)j * DD + d0);
                else        xv[q] = (f4)(0.0f);
            }
        }
        SB0;
        if (k + 1 < TPB) stage_dma(k + 1);   // 9 DMA ops ride behind xv in FIFO
        SB0;

        // Phase B: consuming xv waits at most vmcnt(9) -> DMA stays in flight
#pragma unroll
        for (int r = 0; r < RB; ++r) {
#pragma unroll
            for (int qc = 0; qc < 4; ++qc) {
                f4 q4 = *(const f4*)&qv[buf][(r << 5) + (jh << 4) + (qc << 2)];
                acc[r] += q4.x * xv[qc * 4 + 0];
                acc[r] += q4.y * xv[qc * 4 + 1];
                acc[r] += q4.z * xv[qc * 4 + 2];
                acc[r] += q4.w * xv[qc * 4 + 3];
            }
        }

        if (k + 1 < TPB) {
            VMCNT0; SB0;                     // drain dma(k+1); mostly covered by Phase B
            qcompute(k + 1, buf ^ 1);        // wave-private, no barrier
        }
    };

#pragma unroll 1
    for (int k2 = 0; k2 < TPB; k2 += 2) {
        body(k2,     0);
        body(k2 + 1, 1);
    }

    // ---- epilogue: fold j-halves; lanes 0..31 hold full sums for d0..d0+3 ----
#pragma unroll
    for (int r = 0; r < RB; ++r)
#pragma unroll
        for (int c = 0; c < 4; ++c)
            acc[r][c] += __shfl_xor(acc[r][c], 32);

    if (lane < 32) {
#pragma unroll
        for (int r = 0; r < RB; ++r)
            *(f4*)&ws[(((size_t)js * RG + rg) * RB + r) * DD + d0] = acc[r];
    }
}

// Kernel 2: out[i,:] = PReLU(sum_js partial[js][i,:]) @ W^T + b
__global__ __launch_bounds__(256, 2)
void prelu_linear(const float* __restrict__ alpha,
                  const float* __restrict__ W,
                  const float* __restrict__ b,
                  const float* __restrict__ ws,
                  float* __restrict__ out)
{
    __shared__ float Wt[128 * 129];
    __shared__ float p[16 * 128];
    const int t  = threadIdx.x;
    const int i0 = blockIdx.x * 16;

#pragma unroll
    for (int it = 0; it < 16; ++it) {
        int f  = (it * 256 + t) * 4;
        int d  = f >> 7;
        int kk = f & 127;
        f4 w4 = *(const f4*)(W + f);
        Wt[(kk + 0) * 129 + d] = w4.x;
        Wt[(kk + 1) * 129 + d] = w4.y;
        Wt[(kk + 2) * 129 + d] = w4.z;
        Wt[(kk + 3) * 129 + d] = w4.w;
    }

#pragma unroll
    for (int it = 0; it < 2; ++it) {
        int fi  = it * 256 + t;
        int row = i0 + (fi >> 5);
        int dc  = (fi & 31) << 2;
        if (row < NN) {
            size_t base = (size_t)row * DD + dc;
            f4 v = *(const f4*)(ws + base);
            v += *(const f4*)(ws + base + (size_t)1 * RG * RB * DD);
            v += *(const f4*)(ws + base + (size_t)2 * RG * RB * DD);
            v += *(const f4*)(ws + base + (size_t)3 * RG * RB * DD);
            f4 al = *(const f4*)(alpha + dc);
            f4 pv;
            pv.x = v.x >= 0.f ? v.x : al.x * v.x;
            pv.y = v.y >= 0.f ? v.y : al.y * v.y;
            pv.z = v.z >= 0.f ? v.z : al.z * v.z;
            pv.w = v.w >= 0.f ? v.w : al.w * v.w;
            *(f4*)&p[(row - i0) * 128 + dc] = pv;
        }
    }
    __syncthreads();

    const int d  = t & 127;
    const int rq = t >> 7;
    const float bv = b[d];
    float acc[8];
#pragma unroll
    for (int ri = 0; ri < 8; ++ri) acc[ri] = 0.f;
#pragma unroll 8
    for (int k = 0; k < 128; ++k) {
        float wv = Wt[k * 129 + d];
#pragma unroll
        for (int ri = 0; ri < 8; ++ri)
            acc[ri] += p[(rq * 8 + ri) * 128 + k] * wv;
    }
#pragma unroll
    for (int ri = 0; ri < 8; ++ri) {
        int row = i0 + rq * 8 + ri;
        if (row < NN) out[(size_t)row * DD + d] = acc[ri] + bv;
    }
}

extern "C" void kernel_launch(void* const* d_in, const int* in_sizes, int n_in,
                              void* d_out, int out_size, void* d_ws, size_t ws_size,
                              hipStream_t stream) {
    const float* theta = (const float*)d_in[0];
    const float* T     = (const float*)d_in[1];
    const float* x     = (const float*)d_in[2];
    const float* a     = (const float*)d_in[3];
    const float* alpha = (const float*)d_in[4];
    const float* W     = (const float*)d_in[5];
    const float* b     = (const float*)d_in[6];
    float* out = (float*)d_out;
    float* ws  = (float*)d_ws;

    dim3 g1(RG * JS);                  // 2500 single-wave blocks (one generation)
    diffuse_spmm<<<g1, dim3(64), 0, stream>>>(theta, T, x, a, ws);

    dim3 g2((NN + 15) / 16);           // 313 blocks
    prelu_linear<<<g2, dim3(256), 0, stream>>>(alpha, W, b, ws, out);
}

// Round 9
// 984.480 us; speedup vs baseline: 2.1519x; 2.1519x over previous
//
#include <hip/hip_runtime.h>

#define SS 8
#define NN 5000
#define NNSQ 25000000
#define DD 128
#define RB 4          // rows per block (wave w <-> row w)
#define JS 2          // column chunks (partials)
#define JC 2500       // chunk width
#define JT 256        // tile columns
#define TPB 10        // tiles per chunk (10*256 = 2560 >= 2500)
#define RG 1250       // row groups = NN/RB

typedef float f4 __attribute__((ext_vector_type(4)));

typedef const __attribute__((address_space(1))) void glb_void;
typedef __attribute__((address_space(3))) void lds_void;

__device__ __forceinline__ void gld_lds16(const void* g, void* l) {
    __builtin_amdgcn_global_load_lds((glb_void*)g, (lds_void*)l, 16, 0, 0);
}

#define VMCNT0 asm volatile("s_waitcnt vmcnt(0)" ::: "memory")
#define SB0    __builtin_amdgcn_sched_barrier(0)

// R5-proven schedule; tile geometry 4 rows x 256 cols so every DMA instruction
// reads one contiguous 1024 B row-run (halves misalignment over-fetch), and
// LDS 44 KB -> 3 blocks/CU (drain windows of 3 independent blocks interleave).
__global__ __launch_bounds__(256, 3)
void diffuse_spmm(const float* __restrict__ theta,
                  const float* __restrict__ Tm,
                  const float* __restrict__ x,
                  const float* __restrict__ am,
                  float* __restrict__ ws)
{
    __shared__ float stg[SS + 1][RB][JT];   // 36 KB: 8 T slices + a; [slice][row][col]
    __shared__ float qv[2][RB][JT];         // 8 KB double-buffered q tile

    const int t    = threadIdx.x;
    const int wid  = t >> 6;                // wave = row 0..3
    const int lane = t & 63;
    const int rg   = blockIdx.x % RG;
    const int js   = blockIdx.x / RG;
    const int i0   = rg * RB;
    const int jc   = js * JC;
    const int jend = (jc + JC < NN) ? (jc + JC) : NN;

    // staging / q-compute mapping: lane covers cols lane*4..+3 of row wid
    const int qcol = lane << 2;
    // Phase B mapping: d-quad x 16-col j-subgroup
    const int d0 = (lane & 31) << 2;
    const int h  = t >> 5;                  // 0..7

    float th[SS];
#pragma unroll
    for (int s = 0; s < SS; ++s) th[s] = theta[s];

    // DMA tile k: 9 instrs/wave, each one contiguous 1024 B row-run. 0 VGPR cost.
    auto stage_dma = [&](int k) {
        const int jg = jc + k * JT + qcol;
        if (jg < NN) {                      // per-lane mask (fault safety)
            const size_t goff = (size_t)(i0 + wid) * NN + jg;
#pragma unroll
            for (int s = 0; s < SS; ++s)
                gld_lds16(Tm + (size_t)s * NNSQ + goff, &stg[s][wid][0]);
            gld_lds16(am + goff, &stg[SS][wid][0]);
        }
    };

    // q for tile k -> qv[buf]; wave reads only its OWN staged row
    auto qcompute = [&](int k, int buf) {
        const int jg = jc + k * JT + qcol;
        f4 ssum = (*(const f4*)&stg[0][wid][qcol]) * th[0];
#pragma unroll
        for (int s = 1; s < SS; ++s)
            ssum += (*(const f4*)&stg[s][wid][qcol]) * th[s];
        f4 q = (*(const f4*)&stg[SS][wid][qcol]) * ssum;
        if (jg >= jend) q = (f4)(0.0f);     // chunk/global boundary mask
        *(f4*)&qv[buf][wid][qcol] = q;
    };

    f4 acc[RB];
#pragma unroll
    for (int r = 0; r < RB; ++r) acc[r] = (f4)(0.0f);

    // prologue: stage tile 0, drain, q(0), publish
    stage_dma(0);
    VMCNT0; SB0;
    qcompute(0, 0);
    __syncthreads();

    int buf = 0;
    for (int k = 0; k < TPB; ++k) {
        // ---- pass-A x loads: FIFO head ----
        f4 xvA[16];
        {
            const int jb = jc + k * JT + (h << 4);
#pragma unroll
            for (int q = 0; q < 16; ++q) {
                const int j = jb + q;
                if (j < NN) xvA[q] = *(const f4*)(x + (size_t)j * DD + d0);
                else        xvA[q] = (f4)(0.0f);
            }
        }
        SB0;
        // ---- next tile's 9 DMAs: FIFO tail (in flight through pass A) ----
        if (k + 1 < TPB) stage_dma(k + 1);
        SB0;

        // ---- Phase B pass A (cols 0..127): consuming xvA waits vmcnt<=9 ----
#pragma unroll
        for (int qc = 0; qc < 4; ++qc)
#pragma unroll
            for (int r = 0; r < RB; ++r) {
                f4 q4 = *(const f4*)&qv[buf][r][(h << 4) + (qc << 2)];
                acc[r] += q4.x * xvA[qc * 4 + 0];
                acc[r] += q4.y * xvA[qc * 4 + 1];
                acc[r] += q4.z * xvA[qc * 4 + 2];
                acc[r] += q4.w * xvA[qc * 4 + 3];
            }

        // ---- pass-B x loads (behind DMAs; their use doubles as the drain) ----
        f4 xvB[16];
        {
            const int jb = jc + k * JT + 128 + (h << 4);
#pragma unroll
            for (int q = 0; q < 16; ++q) {
                const int j = jb + q;
                if (j < NN) xvB[q] = *(const f4*)(x + (size_t)j * DD + d0);
                else        xvB[q] = (f4)(0.0f);
            }
        }
        SB0;
        // ---- Phase B pass B (cols 128..255) ----
#pragma unroll
        for (int qc = 0; qc < 4; ++qc)
#pragma unroll
            for (int r = 0; r < RB; ++r) {
                f4 q4 = *(const f4*)&qv[buf][r][128 + (h << 4) + (qc << 2)];
                acc[r] += q4.x * xvB[qc * 4 + 0];
                acc[r] += q4.y * xvB[qc * 4 + 1];
                acc[r] += q4.z * xvB[qc * 4 + 2];
                acc[r] += q4.w * xvB[qc * 4 + 3];
            }

        if (k + 1 < TPB) {
            VMCNT0; SB0;                    // residual drain (mostly complete already)
            qcompute(k + 1, buf ^ 1);       // own-wave rows only
            __syncthreads();                // publish qv[buf^1]
            buf ^= 1;
        }
    }

    // ---- epilogue: fold j-halves; cross-wave reduce via LDS (alias qv) ----
#pragma unroll
    for (int r = 0; r < RB; ++r)
#pragma unroll
        for (int c = 0; c < 4; ++c)
            acc[r][c] += __shfl_xor(acc[r][c], 32);

    __syncthreads();                        // qv dead -> safe to alias
    float* red = (float*)&qv[0][0][0];      // 8 KB >= 3*4*128*4
    if (wid > 0 && lane < 32) {
#pragma unroll
        for (int r = 0; r < RB; ++r)
            *(f4*)&red[((wid - 1) * RB + r) * DD + d0] = acc[r];
    }
    __syncthreads();
    if (wid == 0 && lane < 32) {
#pragma unroll
        for (int r = 0; r < RB; ++r) {
            f4 v = acc[r];
#pragma unroll
            for (int p = 0; p < 3; ++p)
                v += *(const f4*)&red[(p * RB + r) * DD + d0];
            *(f4*)&ws[(((size_t)js * RG + rg) * RB + r) * DD + d0] = v;
        }
    }
}

// Kernel 2: out[i,:] = PReLU(sum_js partial[js][i,:]) @ W^T + b
__global__ __launch_bounds__(256, 2)
void prelu_linear(const float* __restrict__ alpha,
                  const float* __restrict__ W,
                  const float* __restrict__ b,
                  const float* __restrict__ ws,
                  float* __restrict__ out)
{
    __shared__ float Wt[128 * 129];
    __shared__ float p[16 * 128];
    const int t  = threadIdx.x;
    const int i0 = blockIdx.x * 16;

#pragma unroll
    for (int it = 0; it < 16; ++it) {
        int f  = (it * 256 + t) * 4;
        int d  = f >> 7;
        int kk = f & 127;
        f4 w4 = *(const f4*)(W + f);
        Wt[(kk + 0) * 129 + d] = w4.x;
        Wt[(kk + 1) * 129 + d] = w4.y;
        Wt[(kk + 2) * 129 + d] = w4.z;
        Wt[(kk + 3) * 129 + d] = w4.w;
    }

#pragma unroll
    for (int it = 0; it < 2; ++it) {
        int fi  = it * 256 + t;
        int row = i0 + (fi >> 5);
        int dc  = (fi & 31) << 2;
        if (row < NN) {
            size_t base = (size_t)row * DD + dc;
            f4 v = *(const f4*)(ws + base);
            v += *(const f4*)(ws + base + (size_t)RG * RB * DD);   // 2nd partial
            f4 al = *(const f4*)(alpha + dc);
            f4 pv;
            pv.x = v.x >= 0.f ? v.x : al.x * v.x;
            pv.y = v.y >= 0.f ? v.y : al.y * v.y;
            pv.z = v.z >= 0.f ? v.z : al.z * v.z;
            pv.w = v.w >= 0.f ? v.w : al.w * v.w;
            *(f4*)&p[(row - i0) * 128 + dc] = pv;
        }
    }
    __syncthreads();

    const int d  = t & 127;
    const int rq = t >> 7;
    const float bv = b[d];
    float acc[8];
#pragma unroll
    for (int ri = 0; ri < 8; ++ri) acc[ri] = 0.f;
#pragma unroll 8
    for (int k = 0; k < 128; ++k) {
        float wv = Wt[k * 129 + d];
#pragma unroll
        for (int ri = 0; ri < 8; ++ri)
            acc[ri] += p[(rq * 8 + ri) * 128 + k] * wv;
    }
#pragma unroll
    for (int ri = 0; ri < 8; ++ri) {
        int row = i0 + rq * 8 + ri;
        if (row < NN) out[(size_t)row * DD + d] = acc[ri] + bv;
    }
}

extern "C" void kernel_launch(void* const* d_in, const int* in_sizes, int n_in,
                              void* d_out, int out_size, void* d_ws, size_t ws_size,
                              hipStream_t stream) {
    const float* theta = (const float*)d_in[0];
    const float* T     = (const float*)d_in[1];
    const float* x     = (const float*)d_in[2];
    const float* a     = (const float*)d_in[3];
    const float* alpha = (const float*)d_in[4];
    const float* W     = (const float*)d_in[5];
    const float* b     = (const float*)d_in[6];
    float* out = (float*)d_out;
    float* ws  = (float*)d_ws;

    dim3 g1(RG * JS);                 // 2500 blocks (4 waves each)
    diffuse_spmm<<<g1, dim3(256), 0, stream>>>(theta, T, x, a, ws);

    dim3 g2((NN + 15) / 16);          // 313 blocks
    prelu_linear<<<g2, dim3(256), 0, stream>>>(alpha, W, b, ws, out);
}

// Round 10
// 555.425 us; speedup vs baseline: 3.8142x; 1.7725x over previous
//
#include <hip/hip_runtime.h>

#define SS 8
#define NN 5000
#define NNSQ 25000000
#define DD 128
#define RB 4          // rows per block; wave w <-> row w
#define JS 2          // column chunks (partials)
#define JC 2500       // chunk width
#define JT 256        // tile columns
#define TPB 10        // tiles per chunk
#define RG 1250       // row groups = NN/RB

typedef float f4 __attribute__((ext_vector_type(4)));

typedef const __attribute__((address_space(1))) void glb_void;
typedef __attribute__((address_space(3))) void lds_void;

__device__ __forceinline__ void gld_lds16(const void* g, void* l) {
    __builtin_amdgcn_global_load_lds((glb_void*)g, (lds_void*)l, 16, 0, 0);
}

#define VMCNT0 asm volatile("s_waitcnt vmcnt(0)" ::: "memory")
#define SB0    __builtin_amdgcn_sched_barrier(0)

// R5-proven schedule, 4x256 tile geometry, x consumed in 8-f4 batches so peak
// register liveness (~90) fits the allocator's empirical 128-VGPR budget.
__global__ __launch_bounds__(256, 2)
void diffuse_spmm(const float* __restrict__ theta,
                  const float* __restrict__ Tm,
                  const float* __restrict__ x,
                  const float* __restrict__ am,
                  float* __restrict__ ws)
{
    __shared__ float stg[SS + 1][RB][JT];   // 36,864 B: slices 0..7 = T, 8 = a
    __shared__ float qv[2][RB][JT];         // 8,192 B double-buffered q tile

    const int t    = threadIdx.x;
    const int wid  = t >> 6;                // wave = row 0..3
    const int lane = t & 63;
    const int rg   = blockIdx.x % RG;
    const int js   = blockIdx.x / RG;
    const int i0   = rg * RB;
    const int jc   = js * JC;
    const int jend = (jc + JC < NN) ? (jc + JC) : NN;

    const int qcol = lane << 2;             // staging col: lane l <-> cols 4l..4l+3
    const int d0   = (lane & 31) << 2;      // Phase B d-quad
    const int h    = t >> 5;                // Phase B 16-col j-subgroup (0..7)

    float th[SS];
#pragma unroll
    for (int s = 0; s < SS; ++s) th[s] = theta[s];

    // DMA tile k: 9 instrs/wave, each one contiguous 1024 B row-run. 0 VGPR cost.
    auto stage_dma = [&](int k) {
        const int jg = jc + k * JT + qcol;
        if (jg < NN) {                      // per-lane exec mask
            const size_t goff = (size_t)(i0 + wid) * NN + jg;
#pragma unroll
            for (int s = 0; s < SS; ++s)
                gld_lds16(Tm + (size_t)s * NNSQ + goff, &stg[s][wid][0]);
            gld_lds16(am + goff, &stg[SS][wid][0]);
        }
    };

    // q for tile k -> qv[buf]; wave reads/writes only its OWN row (no barrier dep)
    auto qcompute = [&](int k, int buf) {
        const int jg = jc + k * JT + qcol;
        f4 ssum = (*(const f4*)&stg[0][wid][qcol]) * th[0];
#pragma unroll
        for (int s = 1; s < SS; ++s)
            ssum += (*(const f4*)&stg[s][wid][qcol]) * th[s];
        f4 q = (*(const f4*)&stg[SS][wid][qcol]) * ssum;
        if (jg >= jend) q = (f4)(0.0f);     // chunk/global boundary mask
        *(f4*)&qv[buf][wid][qcol] = q;
    };

    f4 acc[RB];
#pragma unroll
    for (int r = 0; r < RB; ++r) acc[r] = (f4)(0.0f);

    // prologue
    stage_dma(0);
    VMCNT0; SB0;
    qcompute(0, 0);
    __syncthreads();

#pragma unroll 1
    for (int k = 0; k < TPB; ++k) {
        const int jb = jc + k * JT + (h << 4);
        const float* qp = &qv[k & 1][0][0];

        // ---- batch A x loads: FIFO head ----
        f4 xa[8];
#pragma unroll
        for (int q = 0; q < 8; ++q) {
            const int j = jb + q;
            xa[q] = (j < NN) ? *(const f4*)(x + (size_t)j * DD + d0) : (f4)(0.0f);
        }
        SB0;
        // ---- next tile's 9 DMAs: FIFO tail ----
        if (k + 1 < TPB) stage_dma(k + 1);
        SB0;

        // cols (h<<4) + 0..7  (consuming xa waits vmcnt<=9: DMA stays in flight)
#pragma unroll
        for (int qc = 0; qc < 2; ++qc)
#pragma unroll
            for (int r = 0; r < RB; ++r) {
                f4 q4 = *(const f4*)&qp[r * JT + (h << 4) + (qc << 2)];
                acc[r] += q4.x * xa[qc * 4 + 0];
                acc[r] += q4.y * xa[qc * 4 + 1];
                acc[r] += q4.z * xa[qc * 4 + 2];
                acc[r] += q4.w * xa[qc * 4 + 3];
            }

        // ---- batch B: cols (h<<4) + 8..15 ----
        f4 xb[8];
#pragma unroll
        for (int q = 0; q < 8; ++q) {
            const int j = jb + 8 + q;
            xb[q] = (j < NN) ? *(const f4*)(x + (size_t)j * DD + d0) : (f4)(0.0f);
        }
#pragma unroll
        for (int qc = 0; qc < 2; ++qc)
#pragma unroll
            for (int r = 0; r < RB; ++r) {
                f4 q4 = *(const f4*)&qp[r * JT + (h << 4) + 8 + (qc << 2)];
                acc[r] += q4.x * xb[qc * 4 + 0];
                acc[r] += q4.y * xb[qc * 4 + 1];
                acc[r] += q4.z * xb[qc * 4 + 2];
                acc[r] += q4.w * xb[qc * 4 + 3];
            }

        // ---- batch C: cols 128 + (h<<4) + 0..7 ----
        f4 xc[8];
#pragma unroll
        for (int q = 0; q < 8; ++q) {
            const int j = jb + 128 + q;
            xc[q] = (j < NN) ? *(const f4*)(x + (size_t)j * DD + d0) : (f4)(0.0f);
        }
#pragma unroll
        for (int qc = 0; qc < 2; ++qc)
#pragma unroll
            for (int r = 0; r < RB; ++r) {
                f4 q4 = *(const f4*)&qp[r * JT + 128 + (h << 4) + (qc << 2)];
                acc[r] += q4.x * xc[qc * 4 + 0];
                acc[r] += q4.y * xc[qc * 4 + 1];
                acc[r] += q4.z * xc[qc * 4 + 2];
                acc[r] += q4.w * xc[qc * 4 + 3];
            }

        // ---- batch D: cols 128 + (h<<4) + 8..15 ----
        f4 xd[8];
#pragma unroll
        for (int q = 0; q < 8; ++q) {
            const int j = jb + 136 + q;
            xd[q] = (j < NN) ? *(const f4*)(x + (size_t)j * DD + d0) : (f4)(0.0f);
        }
#pragma unroll
        for (int qc = 0; qc < 2; ++qc)
#pragma unroll
            for (int r = 0; r < RB; ++r) {
                f4 q4 = *(const f4*)&qp[r * JT + 128 + (h << 4) + 8 + (qc << 2)];
                acc[r] += q4.x * xd[qc * 4 + 0];
                acc[r] += q4.y * xd[qc * 4 + 1];
                acc[r] += q4.z * xd[qc * 4 + 2];
                acc[r] += q4.w * xd[qc * 4 + 3];
            }

        if (k + 1 < TPB) {
            VMCNT0; SB0;                    // residual DMA drain (mostly complete)
            qcompute(k + 1, (k + 1) & 1);   // own-wave row only
            __syncthreads();                // publish qv
        }
    }

    // ---- epilogue: fold j-halves; cross-wave reduce via LDS (alias stage) ----
#pragma unroll
    for (int r = 0; r < RB; ++r)
#pragma unroll
        for (int c = 0; c < 4; ++c)
            acc[r][c] += __shfl_xor(acc[r][c], 32);

    __syncthreads();                        // all waves done with stg -> alias
    float* red = (float*)&stg[0][0][0];     // 6 KB scratch
    if (wid > 0 && lane < 32) {
#pragma unroll
        for (int r = 0; r < RB; ++r)
            *(f4*)&red[((wid - 1) * RB + r) * DD + d0] = acc[r];
    }
    __syncthreads();
    if (wid == 0 && lane < 32) {
#pragma unroll
        for (int r = 0; r < RB; ++r) {
            f4 v = acc[r];
#pragma unroll
            for (int p = 0; p < 3; ++p)
                v += *(const f4*)&red[(p * RB + r) * DD + d0];
            *(f4*)&ws[(((size_t)js * RG + rg) * RB + r) * DD + d0] = v;
        }
    }
}

// Kernel 2: out[i,:] = PReLU(sum_js partial[js][i,:]) @ W^T + b
__global__ __launch_bounds__(256, 2)
void prelu_linear(const float* __restrict__ alpha,
                  const float* __restrict__ W,
                  const float* __restrict__ b,
                  const float* __restrict__ ws,
                  float* __restrict__ out)
{
    __shared__ float Wt[128 * 129];
    __shared__ float p[16 * 128];
    const int t  = threadIdx.x;
    const int i0 = blockIdx.x * 16;

#pragma unroll
    for (int it = 0; it < 16; ++it) {
        int f  = (it * 256 + t) * 4;
        int d  = f >> 7;
        int kk = f & 127;
        f4 w4 = *(const f4*)(W + f);
        Wt[(kk + 0) * 129 + d] = w4.x;
        Wt[(kk + 1) * 129 + d] = w4.y;
        Wt[(kk + 2) * 129 + d] = w4.z;
        Wt[(kk + 3) * 129 + d] = w4.w;
    }

#pragma unroll
    for (int it = 0; it < 2; ++it) {
        int fi  = it * 256 + t;
        int row = i0 + (fi >> 5);
        int dc  = (fi & 31) << 2;
        if (row < NN) {
            size_t base = (size_t)row * DD + dc;
            f4 v = *(const f4*)(ws + base);
            v += *(const f4*)(ws + base + (size_t)RG * RB * DD);   // 2nd partial
            f4 al = *(const f4*)(alpha + dc);
            f4 pv;
            pv.x = v.x >= 0.f ? v.x : al.x * v.x;
            pv.y = v.y >= 0.f ? v.y : al.y * v.y;
            pv.z = v.z >= 0.f ? v.z : al.z * v.z;
            pv.w = v.w >= 0.f ? v.w : al.w * v.w;
            *(f4*)&p[(row - i0) * 128 + dc] = pv;
        }
    }
    __syncthreads();

    const int d  = t & 127;
    const int rq = t >> 7;
    const float bv = b[d];
    float acc[8];
#pragma unroll
    for (int ri = 0; ri < 8; ++ri) acc[ri] = 0.f;
#pragma unroll 8
    for (int k = 0; k < 128; ++k) {
        float wv = Wt[k * 129 + d];
#pragma unroll
        for (int ri = 0; ri < 8; ++ri)
            acc[ri] += p[(rq * 8 + ri) * 128 + k] * wv;
    }
#pragma unroll
    for (int ri = 0; ri < 8; ++ri) {
        int row = i0 + rq * 8 + ri;
        if (row < NN) out[(size_t)row * DD + d] = acc[ri] + bv;
    }
}

extern "C" void kernel_launch(void* const* d_in, const int* in_sizes, int n_in,
                              void* d_out, int out_size, void* d_ws, size_t ws_size,
                              hipStream_t stream) {
    const float* theta = (const float*)d_in[0];
    const float* T     = (const float*)d_in[1];
    const float* x     = (const float*)d_in[2];
    const float* a     = (const float*)d_in[3];
    const float* alpha = (const float*)d_in[4];
    const float* W     = (const float*)d_in[5];
    const float* b     = (const float*)d_in[6];
    float* out = (float*)d_out;
    float* ws  = (float*)d_ws;

    dim3 g1(RG * JS);                 // 2500 blocks (4 waves each)
    diffuse_spmm<<<g1, dim3(256), 0, stream>>>(theta, T, x, a, ws);

    dim3 g2((NN + 15) / 16);          // 313 blocks
    prelu_linear<<<g2, dim3(256), 0, stream>>>(alpha, W, b, ws, out);
}

// Round 11
// 234.763 us; speedup vs baseline: 9.0239x; 2.3659x over previous
//
#include <hip/hip_runtime.h>

#define SS 8
#define NN 5000
#define NNSQ 25000000
#define DD 128
#define RB 8          // rows per block
#define JS 4          // column splits (partials)
#define JT 128        // tile columns
#define TPB 10        // tiles per block
#define RG 625        // row groups

typedef float f4 __attribute__((ext_vector_type(4)));

typedef const __attribute__((address_space(1))) void glb_void;
typedef __attribute__((address_space(3))) void lds_void;

__device__ __forceinline__ void gld_lds16(const void* g, void* l) {
    __builtin_amdgcn_global_load_lds((glb_void*)g, (lds_void*)l, 16, 0, 0);
}

#define VMCNT0 asm volatile("s_waitcnt vmcnt(0)" ::: "memory")
#define SB0    __builtin_amdgcn_sched_barrier(0)

// R5-proven schedule, LDS trimmed 57.6 KB -> 44 KB so 3 blocks/CU co-reside:
// their per-tile drain windows interleave and keep the HBM queue fed.
__global__ __launch_bounds__(256, 2)
void diffuse_spmm(const float* __restrict__ theta,
                  const float* __restrict__ Tm,
                  const float* __restrict__ x,
                  const float* __restrict__ am,
                  float* __restrict__ ws)
{
    // stage: slices 0..7 = T, slice 8 = a. Single buffer, 36,864 B.
    __shared__ float stage[9 * RB * 128];
    __shared__ float qv[2][RB * 128];          // 8,192 B double-buffered q tile
    // total 45,056 B -> 3 blocks/CU; epilogue reduce buffer aliases `stage`

    const int t    = threadIdx.x;
    const int wid  = t >> 6;
    const int lane = t & 63;
    const int rg   = blockIdx.x % RG;
    const int js   = blockIdx.x / RG;
    const int i0   = rg * RB;
    const int tile0 = js * TPB;

    // stage/q-compute mapping: thread touches only rows its own wave DMA'd
    const int ar = (wid << 1) + (lane >> 5);   // row 0..7 (wave w owns rows 2w,2w+1)
    const int aj = (lane & 31) << 2;           // col quad offset 0..124
    // Phase B mapping
    const int h  = t >> 5;                     // j-subgroup (16 consecutive cols)
    const int d0 = (t & 31) << 2;

    float th[SS];
#pragma unroll
    for (int s = 0; s < SS; ++s) th[s] = theta[s];

    // DMA one tile's T/a rows into stage (no VGPR cost).
    // LDS dest is wave-uniform; lanes 0..31 -> row 2w (512 B), 32..63 -> row 2w+1.
    auto stage_dma = [&](int tt) {
        const int j = tt * JT + aj;
        if (j < NN) {                          // ragged last tile: mask lanes
            const size_t goff = (size_t)(i0 + ar) * NN + j;
#pragma unroll
            for (int s = 0; s < SS; ++s)
                gld_lds16(Tm + (size_t)s * NNSQ + goff,
                          &stage[s * (RB * 128) + (wid << 1) * 128]);
            gld_lds16(am + goff, &stage[SS * (RB * 128) + (wid << 1) * 128]);
        }
    };

    // q-compute for tile tt -> qv[n] (reads only own-wave staged rows)
    auto qcompute = [&](int tt, int n) {
        const int j = tt * JT + aj;
        const int lbase = ar * 128 + aj;
        f4 ssum = (*(const f4*)&stage[0 * (RB * 128) + lbase]) * th[0];
#pragma unroll
        for (int s = 1; s < SS; ++s)
            ssum += (*(const f4*)&stage[s * (RB * 128) + lbase]) * th[s];
        f4 av = *(const f4*)&stage[SS * (RB * 128) + lbase];
        f4 q  = av * ssum;
        if (j >= NN) q = (f4)(0.0f);           // zero cols beyond N (stale LDS)
        *(f4*)&qv[n][ar * 128 + aj] = q;
    };

    f4 acc[RB];
#pragma unroll
    for (int r = 0; r < RB; ++r) acc[r] = (f4)(0.0f);

    // prologue: stage tile0, compute qv[0]
    stage_dma(tile0);
    VMCNT0;
    SB0;
    qcompute(tile0, 0);
    __syncthreads();

    for (int k = 0; k < TPB; ++k) {
        const int tt = tile0 + k;

        // ---- x loads for THIS tile: FIRST into the vmcnt FIFO ----
        f4 xv[16];                             // static indexing only
        {
            const int jb = tt * JT + (h << 4);
#pragma unroll
            for (int q = 0; q < 16; ++q) {
                const int j = jb + q;
                if (j < NN) xv[q] = *(const f4*)(x + (size_t)j * DD + d0);
                else        xv[q] = (f4)(0.0f);
            }
        }
        SB0;
        // ---- next tile's T/a DMA: LAST into the FIFO (0 registers) ----
        if (k + 1 < TPB) stage_dma(tt + 1);
        SB0;

        // ---- Phase B: acc[r] += qv[r][jj] * x[jj][d0..d0+3] ----
        // consuming xv waits vmcnt(9) at worst -> DMA stays in flight
        const float* qp = &qv[k & 1][0];
#pragma unroll
        for (int qc = 0; qc < 4; ++qc) {
#pragma unroll
            for (int r = 0; r < RB; ++r) {
                f4 q = *(const f4*)&qp[r * 128 + (h << 4) + (qc << 2)];
                acc[r] += q.x * xv[qc * 4 + 0];
                acc[r] += q.y * xv[qc * 4 + 1];
                acc[r] += q.z * xv[qc * 4 + 2];
                acc[r] += q.w * xv[qc * 4 + 3];
            }
        }

        if (k + 1 < TPB) {
            // DMA issued ~1000+ cycles ago; drain is cheap now
            VMCNT0;
            SB0;
            qcompute(tt + 1, (k + 1) & 1);     // own-wave rows -> no barrier needed
            __syncthreads();                   // publish qv; orders stage reuse
        }
    }

    // ---- epilogue: reduce h-pairs in wave, then cross-wave via LDS ----
#pragma unroll
    for (int r = 0; r < RB; ++r)
#pragma unroll
        for (int c = 0; c < 4; ++c)
            acc[r][c] += __shfl_xor(acc[r][c], 32);

    __syncthreads();                           // loop done; stage is dead -> alias
    float* red = &stage[0];                    // 12,288 B scratch fits in 36,864
    if (wid > 0 && lane < 32) {
#pragma unroll
        for (int r = 0; r < RB; ++r)
            *(f4*)&red[((wid - 1) * RB + r) * 128 + d0] = acc[r];
    }
    __syncthreads();
    if (wid == 0 && lane < 32) {
#pragma unroll
        for (int r = 0; r < RB; ++r) {
            f4 v = acc[r];
#pragma unroll
            for (int p = 0; p < 3; ++p)
                v += *(const f4*)&red[(p * RB + r) * 128 + d0];
            *(f4*)&ws[(((size_t)js * RG + rg) * RB + r) * DD + d0] = v;
        }
    }
}

// Kernel 2: out[i,:] = PReLU(sum_js partial[js][i,:]) @ W^T + b
__global__ __launch_bounds__(256, 2)
void prelu_linear(const float* __restrict__ alpha,
                  const float* __restrict__ W,
                  const float* __restrict__ b,
                  const float* __restrict__ ws,
                  float* __restrict__ out)
{
    __shared__ float Wt[128 * 129];
    __shared__ float p[16 * 128];
    const int t  = threadIdx.x;
    const int i0 = blockIdx.x * 16;

#pragma unroll
    for (int it = 0; it < 16; ++it) {
        int f  = (it * 256 + t) * 4;
        int d  = f >> 7;
        int kk = f & 127;
        f4 w4 = *(const f4*)(W + f);
        Wt[(kk + 0) * 129 + d] = w4.x;
        Wt[(kk + 1) * 129 + d] = w4.y;
        Wt[(kk + 2) * 129 + d] = w4.z;
        Wt[(kk + 3) * 129 + d] = w4.w;
    }

#pragma unroll
    for (int it = 0; it < 2; ++it) {
        int fi  = it * 256 + t;
        int row = i0 + (fi >> 5);
        int dc  = (fi & 31) << 2;
        if (row < NN) {
            size_t base = (size_t)row * DD + dc;
            f4 v = *(const f4*)(ws + base);
            v += *(const f4*)(ws + base + (size_t)1 * RG * RB * DD);
            v += *(const f4*)(ws + base + (size_t)2 * RG * RB * DD);
            v += *(const f4*)(ws + base + (size_t)3 * RG * RB * DD);
            f4 al = *(const f4*)(alpha + dc);
            f4 pv;
            pv.x = v.x >= 0.f ? v.x : al.x * v.x;
            pv.y = v.y >= 0.f ? v.y : al.y * v.y;
            pv.z = v.z >= 0.f ? v.z : al.z * v.z;
            pv.w = v.w >= 0.f ? v.w : al.w * v.w;
            *(f4*)&p[(row - i0) * 128 + dc] = pv;
        }
    }
    __syncthreads();

    const int d  = t & 127;
    const int rq = t >> 7;
    const float bv = b[d];
    float acc[8];
#pragma unroll
    for (int ri = 0; ri < 8; ++ri) acc[ri] = 0.f;
#pragma unroll 8
    for (int k = 0; k < 128; ++k) {
        float wv = Wt[k * 129 + d];
#pragma unroll
        for (int ri = 0; ri < 8; ++ri)
            acc[ri] += p[(rq * 8 + ri) * 128 + k] * wv;
    }
#pragma unroll
    for (int ri = 0; ri < 8; ++ri) {
        int row = i0 + rq * 8 + ri;
        if (row < NN) out[(size_t)row * DD + d] = acc[ri] + bv;
    }
}

extern "C" void kernel_launch(void* const* d_in, const int* in_sizes, int n_in,
                              void* d_out, int out_size, void* d_ws, size_t ws_size,
                              hipStream_t stream) {
    const float* theta = (const float*)d_in[0];
    const float* T     = (const float*)d_in[1];
    const float* x     = (const float*)d_in[2];
    const float* a     = (const float*)d_in[3];
    const float* alpha = (const float*)d_in[4];
    const float* W     = (const float*)d_in[5];
    const float* b     = (const float*)d_in[6];
    float* out = (float*)d_out;
    float* ws  = (float*)d_ws;

    dim3 blk(256);
    dim3 g1(RG * JS);                 // 2500 blocks
    diffuse_spmm<<<g1, blk, 0, stream>>>(theta, T, x, a, ws);

    dim3 g2((NN + 15) / 16);          // 313 blocks
    prelu_linear<<<g2, blk, 0, stream>>>(alpha, W, b, ws, out);
}